// Round 1
// baseline (110.956 us; speedup 1.0000x reference)
//
#include <hip/hip_runtime.h>
#include <math.h>

#define BB 4
#define LL 256
#define TT 256
#define DD 512

// tanh(x) = 1 - 2/(exp(2x)+1);  exp(2x) = exp2(x * 2/ln2)
__device__ __forceinline__ float fast_tanh(float x) {
  float e = exp2f(x * 2.885390081777927f);      // v_exp_f32
  return fmaf(-2.0f, __builtin_amdgcn_rcpf(e + 1.0f), 1.0f);
}

// ---------------------------------------------------------------------------
// Kernel 1: combined projection GEMM.
// Rows 0..1023:  item1 = x @ W1^T + b1
// Rows 1024..2047: item2 = mem @ W2^T + b2
// C[m,e] = dot(A_row_m, W_row_e)  (both K-contiguous -> "NT" dot of rows)
// 64x64 tile, BK=16, 256 threads, 4x4 accum per thread.
// LDS stored k-major (As[kk][row]) so fragment reads are ds_read_b128.
// ---------------------------------------------------------------------------
__global__ __launch_bounds__(256) void proj_gemm(
    const float* __restrict__ x, const float* __restrict__ mem,
    const float* __restrict__ W1, const float* __restrict__ b1,
    const float* __restrict__ W2, const float* __restrict__ b2,
    float* __restrict__ item1, float* __restrict__ item2)
{
  constexpr int BK = 16;
  __shared__ __align__(16) float As[BK][64];
  __shared__ __align__(16) float Bs[BK][64];

  const int tid = threadIdx.x;
  const int m0 = blockIdx.x * 64;      // 0..2047 in steps of 64
  const int n0 = blockIdx.y * 64;      // 0..511  in steps of 64
  const bool second = (m0 >= BB * LL);

  const float* A    = second ? mem + (size_t)(m0 - BB * LL) * DD
                             : x   + (size_t)m0 * DD;
  const float* W    = second ? W2 : W1;
  const float* bias = second ? b2 : b1;
  float* C          = second ? item2 + (size_t)(m0 - BB * LL) * DD
                             : item1 + (size_t)m0 * DD;

  // staging map: thread -> (row 0..63, k-quad 0..3), 16 consecutive floats per
  // 4-thread group -> coalesced 64B chunks
  const int lrow = tid >> 2;
  const int lk   = (tid & 3) * 4;
  // compute map: 16x16 threads, 4x4 outputs each
  const int tx = tid & 15;
  const int ty = tid >> 4;

  float c[4][4] = {};

  for (int kc = 0; kc < DD; kc += BK) {
    float4 av = *(const float4*)(A + (size_t)lrow * DD + kc + lk);
    float4 wv = *(const float4*)(W + (size_t)(n0 + lrow) * DD + kc + lk);
    __syncthreads();   // previous iteration's reads done
    As[lk + 0][lrow] = av.x; As[lk + 1][lrow] = av.y;
    As[lk + 2][lrow] = av.z; As[lk + 3][lrow] = av.w;
    Bs[lk + 0][lrow] = wv.x; Bs[lk + 1][lrow] = wv.y;
    Bs[lk + 2][lrow] = wv.z; Bs[lk + 3][lrow] = wv.w;
    __syncthreads();
#pragma unroll
    for (int kk = 0; kk < BK; ++kk) {
      float4 a  = *(const float4*)(&As[kk][ty * 4]);   // broadcast over tx
      float4 bv = *(const float4*)(&Bs[kk][tx * 4]);   // 2-way (free)
      float a4[4] = {a.x, a.y, a.z, a.w};
      float b4[4] = {bv.x, bv.y, bv.z, bv.w};
#pragma unroll
      for (int i = 0; i < 4; ++i)
#pragma unroll
        for (int j = 0; j < 4; ++j)
          c[i][j] = fmaf(a4[i], b4[j], c[i][j]);
    }
  }

  float4 bb = *(const float4*)(bias + n0 + tx * 4);
#pragma unroll
  for (int i = 0; i < 4; ++i) {
    float4 o = {c[i][0] + bb.x, c[i][1] + bb.y, c[i][2] + bb.z, c[i][3] + bb.w};
    *(float4*)(C + (size_t)(ty * 4 + i) * DD + n0 + tx * 4) = o;
  }
}

// ---------------------------------------------------------------------------
// Kernel 2: fused masked additive-attention. One 256-thread block per (b,l).
// Phase 1: wave w computes S[t] for t = l+w, l+w+4, ... (lanes split D, 8 each)
// Phase 2: block softmax over S[l..T-1] (1/sum deferred to epilogue)
// Phase 3: out[b,l,:] = (sum_t e_t * mem[b,t,:]) / sum
// ---------------------------------------------------------------------------
__global__ __launch_bounds__(256) void attn_fused(
    const float* __restrict__ item1, const float* __restrict__ item2,
    const float* __restrict__ mem,   const float* __restrict__ wt,
    const float* __restrict__ btp,   const int* __restrict__ mask,
    float* __restrict__ out)
{
  const int l = blockIdx.x;
  const int b = blockIdx.y;
  const int tid  = threadIdx.x;
  const int lane = tid & 63;
  const int wid  = tid >> 6;

  __shared__ float S[TT];
  __shared__ float red[8];

  const int d0 = lane * 8;                 // 64 lanes x 8 = 512 = D
  const float* i1p = item1 + ((size_t)(b * LL + l)) * DD + d0;
  const float4 i1a = *(const float4*)(i1p);
  const float4 i1b = *(const float4*)(i1p + 4);
  const float4 wa  = *(const float4*)(wt + d0);
  const float4 wb  = *(const float4*)(wt + d0 + 4);
  const float  bt  = btp[0];

  // ---- phase 1: scores for t >= l ----
  for (int t = l + wid; t < TT; t += 4) {
    const float* i2p = item2 + ((size_t)(b * TT + t)) * DD + d0;
    const float4 pa = *(const float4*)(i2p);
    const float4 pb = *(const float4*)(i2p + 4);
    float acc0, acc1;
    acc0 = wa.x * fast_tanh(i1a.x + pa.x);
    acc1 = wa.y * fast_tanh(i1a.y + pa.y);
    acc0 = fmaf(wa.z, fast_tanh(i1a.z + pa.z), acc0);
    acc1 = fmaf(wa.w, fast_tanh(i1a.w + pa.w), acc1);
    acc0 = fmaf(wb.x, fast_tanh(i1b.x + pb.x), acc0);
    acc1 = fmaf(wb.y, fast_tanh(i1b.y + pb.y), acc1);
    acc0 = fmaf(wb.z, fast_tanh(i1b.z + pb.z), acc0);
    acc1 = fmaf(wb.w, fast_tanh(i1b.w + pb.w), acc1);
    float acc = acc0 + acc1;
#pragma unroll
    for (int o = 1; o < 64; o <<= 1) acc += __shfl_xor(acc, o);
    if (lane == 0) {
      const bool valid = (mask[b * TT + t] != 0);
      S[t] = valid ? (acc + bt) : -1e30f;
    }
  }
  __syncthreads();

  // ---- phase 2: softmax over t in [l, T) ----
  const int t2 = l + tid;
  float v = (t2 < TT) ? S[t2] : -1e30f;
  float mx = v;
#pragma unroll
  for (int o = 32; o >= 1; o >>= 1) mx = fmaxf(mx, __shfl_xor(mx, o));
  if (lane == 0) red[wid] = mx;
  __syncthreads();
  mx = fmaxf(fmaxf(red[0], red[1]), fmaxf(red[2], red[3]));
  float e = 0.0f;
  if (t2 < TT) { e = __expf(v - mx); S[t2] = e; }
  float sm = e;
#pragma unroll
  for (int o = 32; o >= 1; o >>= 1) sm += __shfl_xor(sm, o);
  if (lane == 0) red[4 + wid] = sm;
  __syncthreads();
  const float rinv = 1.0f / (red[4] + red[5] + red[6] + red[7]);

  // ---- phase 3: PV ----
  const int dd = tid * 2;                  // 256 threads x 2 = 512 = D
  const float* mp = mem + ((size_t)b * TT) * DD + dd;
  float ax = 0.0f, ay = 0.0f;
#pragma unroll 4
  for (int t = l; t < TT; ++t) {
    const float p = S[t];
    const float2 mv = *(const float2*)(mp + (size_t)t * DD);
    ax = fmaf(p, mv.x, ax);
    ay = fmaf(p, mv.y, ay);
  }
  float2 o2 = {ax * rinv, ay * rinv};
  *(float2*)(out + ((size_t)(b * LL + l)) * DD + dd) = o2;
}

extern "C" void kernel_launch(void* const* d_in, const int* in_sizes, int n_in,
                              void* d_out, int out_size, void* d_ws, size_t ws_size,
                              hipStream_t stream) {
  const float* x   = (const float*)d_in[0];
  const float* mem = (const float*)d_in[1];
  const float* W1  = (const float*)d_in[2];
  const float* b1  = (const float*)d_in[3];
  const float* W2  = (const float*)d_in[4];
  const float* b2  = (const float*)d_in[5];
  const float* wt  = (const float*)d_in[6];
  const float* bt  = (const float*)d_in[7];
  const int* mask  = (const int*)d_in[8];
  float* outp = (float*)d_out;

  float* item1 = (float*)d_ws;                         // [B*L, D] fp32 (2 MB)
  float* item2 = item1 + (size_t)BB * LL * DD;         // [B*T, D] fp32 (2 MB)

  proj_gemm<<<dim3((BB * LL + BB * TT) / 64, DD / 64), 256, 0, stream>>>(
      x, mem, W1, b1, W2, b2, item1, item2);
  attn_fused<<<dim3(LL, BB), 256, 0, stream>>>(
      item1, item2, mem, wt, bt, mask, outp);
}

// Round 2
// 94.231 us; speedup vs baseline: 1.1775x; 1.1775x over previous
//
#include <hip/hip_runtime.h>
#include <math.h>

#define BB 4
#define LL 256
#define TT 256
#define DD 512

// tanh(x) = 1 - 2/(exp(2x)+1);  exp(2x) = exp2(x * 2/ln2)
__device__ __forceinline__ float fast_tanh(float x) {
  float e = exp2f(x * 2.885390081777927f);      // v_exp_f32
  return fmaf(-2.0f, __builtin_amdgcn_rcpf(e + 1.0f), 1.0f);
}

// ---------------------------------------------------------------------------
// Kernel 1: combined projection GEMM.
// Rows 0..1023:  item1 = x @ W1^T + b1          (row-major [B*L, D])
// Rows 1024..2047: item2 = mem @ W2^T + b2 -> CHUNKED layout
//   item2c[d>>2][b*T+t][d&3]  (so score kernel reads per-lane float4 coalesced)
// ---------------------------------------------------------------------------
__global__ __launch_bounds__(256) void proj_gemm(
    const float* __restrict__ x, const float* __restrict__ mem,
    const float* __restrict__ W1, const float* __restrict__ b1,
    const float* __restrict__ W2, const float* __restrict__ b2,
    float* __restrict__ item1, float* __restrict__ item2c)
{
  constexpr int BK = 16;
  __shared__ __align__(16) float As[BK][64];
  __shared__ __align__(16) float Bs[BK][64];

  const int tid = threadIdx.x;
  const int m0 = blockIdx.x * 64;      // 0..2047 in steps of 64
  const int n0 = blockIdx.y * 64;      // 0..511  in steps of 64
  const bool second = (m0 >= BB * LL);

  const float* A    = second ? mem + (size_t)(m0 - BB * LL) * DD
                             : x   + (size_t)m0 * DD;
  const float* W    = second ? W2 : W1;
  const float* bias = second ? b2 : b1;

  const int lrow = tid >> 2;
  const int lk   = (tid & 3) * 4;
  const int tx = tid & 15;
  const int ty = tid >> 4;

  float c[4][4] = {};

  for (int kc = 0; kc < DD; kc += BK) {
    float4 av = *(const float4*)(A + (size_t)lrow * DD + kc + lk);
    float4 wv = *(const float4*)(W + (size_t)(n0 + lrow) * DD + kc + lk);
    __syncthreads();
    As[lk + 0][lrow] = av.x; As[lk + 1][lrow] = av.y;
    As[lk + 2][lrow] = av.z; As[lk + 3][lrow] = av.w;
    Bs[lk + 0][lrow] = wv.x; Bs[lk + 1][lrow] = wv.y;
    Bs[lk + 2][lrow] = wv.z; Bs[lk + 3][lrow] = wv.w;
    __syncthreads();
#pragma unroll
    for (int kk = 0; kk < BK; ++kk) {
      float4 a  = *(const float4*)(&As[kk][ty * 4]);
      float4 bv = *(const float4*)(&Bs[kk][tx * 4]);
      float a4[4] = {a.x, a.y, a.z, a.w};
      float b4[4] = {bv.x, bv.y, bv.z, bv.w};
#pragma unroll
      for (int i = 0; i < 4; ++i)
#pragma unroll
        for (int j = 0; j < 4; ++j)
          c[i][j] = fmaf(a4[i], b4[j], c[i][j]);
    }
  }

  float4 bb = *(const float4*)(bias + n0 + tx * 4);
  if (!second) {
    float* C = item1 + (size_t)m0 * DD;
#pragma unroll
    for (int i = 0; i < 4; ++i) {
      float4 o = {c[i][0] + bb.x, c[i][1] + bb.y, c[i][2] + bb.z, c[i][3] + bb.w};
      *(float4*)(C + (size_t)(ty * 4 + i) * DD + n0 + tx * 4) = o;
    }
  } else {
    const int mbase = m0 - BB * LL;
    const int d4 = (n0 >> 2) + tx;
#pragma unroll
    for (int i = 0; i < 4; ++i) {
      float4 o = {c[i][0] + bb.x, c[i][1] + bb.y, c[i][2] + bb.z, c[i][3] + bb.w};
      const int m = mbase + ty * 4 + i;
      *(float4*)(item2c + ((size_t)d4 * (BB * TT) + m) * 4) = o;
    }
  }
}

// ---------------------------------------------------------------------------
// Kernel 2: scores. One wave per task (b, l, 64-wide t-tile), lane = t.
// Exactly the needed tiles (tc >= l>>6): 640 tasks/b, 2560 waves total,
// all equal size: 128 coalesced float4 iterations, zero cross-lane ops.
// ---------------------------------------------------------------------------
__global__ __launch_bounds__(256) void score_kernel(
    const float* __restrict__ item1, const float* __restrict__ item2c,
    const float* __restrict__ wt, const float* __restrict__ btp,
    const int* __restrict__ mask, float* __restrict__ Sg)
{
  const int tid  = threadIdx.x;
  const int lane = tid & 63;
  const int wid  = blockIdx.x * 4 + (tid >> 6);   // 0..2559
  const int b = wid / 640;
  const int u = wid - b * 640;
  int l, tc;
  if (u < 256)      { l = u >> 2;                       tc = u & 3; }
  else if (u < 448) { int v = u - 256; l = 64 + v / 3;  tc = 1 + v % 3; }
  else if (u < 576) { int v = u - 448; l = 128 + (v>>1); tc = 2 + (v & 1); }
  else              { l = 192 + (u - 576);              tc = 3; }

  const int t = tc * 64 + lane;
  const int m = b * TT + t;
  const float4* i2p = (const float4*)item2c + m;           // stride B*T per d4
  const float4* i1p = (const float4*)(item1 + ((size_t)(b * LL + l)) * DD);
  const float4* wtp = (const float4*)wt;

  float a0 = 0.f, a1 = 0.f, a2 = 0.f, a3 = 0.f;
#pragma unroll 4
  for (int d4 = 0; d4 < DD / 4; ++d4) {
    float4 v = i2p[(size_t)d4 * (BB * TT)];
    float4 q = i1p[d4];
    float4 w = wtp[d4];
    a0 = fmaf(w.x, fast_tanh(q.x + v.x), a0);
    a1 = fmaf(w.y, fast_tanh(q.y + v.y), a1);
    a2 = fmaf(w.z, fast_tanh(q.z + v.z), a2);
    a3 = fmaf(w.w, fast_tanh(q.w + v.w), a3);
  }
  float s = (a0 + a1) + (a2 + a3) + btp[0];
  const bool valid = (t >= l) && (mask[m] != 0);
  Sg[((size_t)(b * LL + l)) * TT + t] = valid ? s : -1e30f;
}

// ---------------------------------------------------------------------------
// Kernel 3: softmax + PV. Block = (b, 4 rows). Wave r owns row l0+r softmax;
// P staged in LDS [256][4] (float4 broadcast reads); PV shares mem reads
// across the 4 rows.
// ---------------------------------------------------------------------------
__global__ __launch_bounds__(256) void softmax_pv(
    const float* __restrict__ Sg, const float* __restrict__ mem,
    float* __restrict__ out)
{
  const int l0 = blockIdx.x * 4;
  const int b  = blockIdx.y;
  const int tid  = threadIdx.x;
  const int lane = tid & 63;
  const int r    = tid >> 6;
  const int l    = l0 + r;

  __shared__ __align__(16) float P[TT][4];
  __shared__ float rinvS[4];

  // ---- softmax of row l (wave r) ----
  const float* srow = Sg + ((size_t)(b * LL + l)) * TT;
  const int tbase = lane * 4;
  float4 v = *(const float4*)(srow + tbase);
  float v0 = (tbase + 0 >= l) ? v.x : -1e30f;
  float v1 = (tbase + 1 >= l) ? v.y : -1e30f;
  float v2 = (tbase + 2 >= l) ? v.z : -1e30f;
  float v3 = (tbase + 3 >= l) ? v.w : -1e30f;
  float mx = fmaxf(fmaxf(v0, v1), fmaxf(v2, v3));
#pragma unroll
  for (int o = 1; o < 64; o <<= 1) mx = fmaxf(mx, __shfl_xor(mx, o));
  float e0 = __expf(v0 - mx), e1 = __expf(v1 - mx),
        e2 = __expf(v2 - mx), e3 = __expf(v3 - mx);
  P[tbase + 0][r] = e0; P[tbase + 1][r] = e1;
  P[tbase + 2][r] = e2; P[tbase + 3][r] = e3;
  float sm = (e0 + e1) + (e2 + e3);
#pragma unroll
  for (int o = 1; o < 64; o <<= 1) sm += __shfl_xor(sm, o);
  if (lane == 0) rinvS[r] = 1.0f / sm;
  __syncthreads();

  // ---- PV: threads split D (2 floats each), rows share mem reads ----
  const int dd = tid * 2;
  const float* mp = mem + ((size_t)b * TT) * DD + dd;
  float ax0=0,ay0=0, ax1=0,ay1=0, ax2=0,ay2=0, ax3=0,ay3=0;
#pragma unroll 2
  for (int t = l0; t < TT; ++t) {
    float4 p = *(const float4*)(&P[t][0]);       // broadcast read
    float2 mv = *(const float2*)(mp + (size_t)t * DD);
    ax0 = fmaf(p.x, mv.x, ax0); ay0 = fmaf(p.x, mv.y, ay0);
    ax1 = fmaf(p.y, mv.x, ax1); ay1 = fmaf(p.y, mv.y, ay1);
    ax2 = fmaf(p.z, mv.x, ax2); ay2 = fmaf(p.z, mv.y, ay2);
    ax3 = fmaf(p.w, mv.x, ax3); ay3 = fmaf(p.w, mv.y, ay3);
  }
  float r0 = rinvS[0], r1 = rinvS[1], r2 = rinvS[2], r3 = rinvS[3];
  float* op = out + ((size_t)(b * LL + l0)) * DD + dd;
  float2 o0 = {ax0 * r0, ay0 * r0}; *(float2*)(op)          = o0;
  float2 o1 = {ax1 * r1, ay1 * r1}; *(float2*)(op + DD)     = o1;
  float2 o2 = {ax2 * r2, ay2 * r2}; *(float2*)(op + 2*DD)   = o2;
  float2 o3 = {ax3 * r3, ay3 * r3}; *(float2*)(op + 3*DD)   = o3;
}

extern "C" void kernel_launch(void* const* d_in, const int* in_sizes, int n_in,
                              void* d_out, int out_size, void* d_ws, size_t ws_size,
                              hipStream_t stream) {
  const float* x   = (const float*)d_in[0];
  const float* mem = (const float*)d_in[1];
  const float* W1  = (const float*)d_in[2];
  const float* b1  = (const float*)d_in[3];
  const float* W2  = (const float*)d_in[4];
  const float* b2  = (const float*)d_in[5];
  const float* wt  = (const float*)d_in[6];
  const float* bt  = (const float*)d_in[7];
  const int* mask  = (const int*)d_in[8];
  float* outp = (float*)d_out;

  float* item1  = (float*)d_ws;                          // [B*L, D]      2 MB
  float* item2c = item1 + (size_t)BB * LL * DD;          // [D/4][B*T][4] 2 MB
  float* Sg     = item2c + (size_t)BB * TT * DD;         // [B][L][T]     1 MB

  proj_gemm<<<dim3((BB * LL + BB * TT) / 64, DD / 64), 256, 0, stream>>>(
      x, mem, W1, b1, W2, b2, item1, item2c);
  score_kernel<<<640, 256, 0, stream>>>(item1, item2c, wt, bt, mask, Sg);
  softmax_pv<<<dim3(LL / 4, BB), 256, 0, stream>>>(Sg, mem, outp);
}

// Round 4
// 81.126 us; speedup vs baseline: 1.3677x; 1.1615x over previous
//
#include <hip/hip_runtime.h>
#include <math.h>

#define BB 4
#define LL 256
#define TT 256
#define DD 512

// e^{2x} = exp2(x * 2/ln2)
#define EXP2K 2.885390081777927f

// ---------------------------------------------------------------------------
// Kernel 1: combined projection GEMM, epilogue writes E = exp(2*(proj+bias)).
// Rows 0..1023:   E1 = exp(2*(x@W1^T+b1))   row-major [B*L, D]
// Rows 1024..2047: E2c = exp(2*(mem@W2^T+b2)) CHUNKED [d>>2][b*T+t][d&3]
// 32x64 tile, BK=16, 256 threads, 2x4 accum -> 512 blocks = 2/CU.
// ---------------------------------------------------------------------------
__global__ __launch_bounds__(256) void proj_gemm(
    const float* __restrict__ x, const float* __restrict__ mem,
    const float* __restrict__ W1, const float* __restrict__ b1,
    const float* __restrict__ W2, const float* __restrict__ b2,
    float* __restrict__ E1, float* __restrict__ E2c)
{
  constexpr int BK = 16;
  __shared__ __align__(16) float As[BK][32];
  __shared__ __align__(16) float Bs[BK][64];

  const int tid = threadIdx.x;
  const int m0 = blockIdx.x * 32;      // 0..2047 in steps of 32
  const int n0 = blockIdx.y * 64;      // 0..511  in steps of 64
  const bool second = (m0 >= BB * LL);

  const float* A    = second ? mem + (size_t)(m0 - BB * LL) * DD
                             : x   + (size_t)m0 * DD;
  const float* W    = second ? W2 : W1;
  const float* bias = second ? b2 : b1;

  const int brow = tid >> 2;
  const int bk   = (tid & 3) * 4;
  const int arow = (tid & 127) >> 2;
  const int tx = tid & 15;
  const int ty = tid >> 4;

  float c[2][4] = {};

  for (int kc = 0; kc < DD; kc += BK) {
    float4 av;
    if (tid < 128) av = *(const float4*)(A + (size_t)arow * DD + kc + bk);
    float4 wv = *(const float4*)(W + (size_t)(n0 + brow) * DD + kc + bk);
    __syncthreads();
    if (tid < 128) {
      As[bk + 0][arow] = av.x; As[bk + 1][arow] = av.y;
      As[bk + 2][arow] = av.z; As[bk + 3][arow] = av.w;
    }
    Bs[bk + 0][brow] = wv.x; Bs[bk + 1][brow] = wv.y;
    Bs[bk + 2][brow] = wv.z; Bs[bk + 3][brow] = wv.w;
    __syncthreads();
#pragma unroll
    for (int kk = 0; kk < BK; ++kk) {
      float2 a  = *(const float2*)(&As[kk][ty * 2]);
      float4 bv = *(const float4*)(&Bs[kk][tx * 4]);
      c[0][0] = fmaf(a.x, bv.x, c[0][0]);
      c[0][1] = fmaf(a.x, bv.y, c[0][1]);
      c[0][2] = fmaf(a.x, bv.z, c[0][2]);
      c[0][3] = fmaf(a.x, bv.w, c[0][3]);
      c[1][0] = fmaf(a.y, bv.x, c[1][0]);
      c[1][1] = fmaf(a.y, bv.y, c[1][1]);
      c[1][2] = fmaf(a.y, bv.z, c[1][2]);
      c[1][3] = fmaf(a.y, bv.w, c[1][3]);
    }
  }

  float4 bb = *(const float4*)(bias + n0 + tx * 4);
#pragma unroll
  for (int i = 0; i < 2; ++i) {
    float4 o;
    o.x = exp2f((c[i][0] + bb.x) * EXP2K);
    o.y = exp2f((c[i][1] + bb.y) * EXP2K);
    o.z = exp2f((c[i][2] + bb.z) * EXP2K);
    o.w = exp2f((c[i][3] + bb.w) * EXP2K);
    const int m = ty * 2 + i;
    if (!second) {
      *(float4*)(E1 + (size_t)(m0 + m) * DD + n0 + tx * 4) = o;
    } else {
      const int mrow = m0 - BB * LL + m;
      const int d4 = (n0 >> 2) + tx;
      *(float4*)(E2c + ((size_t)d4 * (BB * TT) + mrow) * 4) = o;
    }
  }
}

// ---------------------------------------------------------------------------
// Kernel 2: scores via exp-product trick.
//   tanh(q+v) = 1 - 2/(Eq*Ev+1);  S = const - 2*sum_d w_d/(Eq*Ev+1)
// (const drops out of softmax -> store sum w*r only).
// One wave per (b, l-PAIR, 32-wide t-tile): lanes 0..31 cover d[0:256) for
// 32 t values, lanes 32..63 cover d[256:512); one shfl_xor(32) combines.
// Exact task map: group g = lp>>4 needs tiles tc in [g,8) -> 576 tasks/b,
// 2304 equal waves. Single Sg buffer [B][L][T] (1 MB) -> total ws 5 MB
// (the 6 MB R3 layout overran ws_size and corrupted an input buffer).
// ---------------------------------------------------------------------------
__global__ __launch_bounds__(256) void score_kernel(
    const float* __restrict__ E1, const float* __restrict__ E2c,
    const float* __restrict__ wt, float* __restrict__ Sg)
{
  const int tid  = threadIdx.x;
  const int lane = tid & 63;
  const int tl   = lane & 31;
  const int half = lane >> 5;
  const int wid  = blockIdx.x * 4 + (tid >> 6);   // 0..2303
  const int b = wid / 576;
  const int u = wid - b * 576;
  // cumulative task count before group g: C(g) = 8*g*(17-g)
  int g;
  if (u < 240)      g = (u < 128) ? 0 : 1;
  else if (u < 416) g = (u < 336) ? 2 : 3;
  else if (u < 528) g = (u < 480) ? 4 : 5;
  else              g = (u < 560) ? 6 : 7;
  const int v   = u - 8 * g * (17 - g);
  const int wdt = 8 - g;                  // tiles per l-pair in this group
  const int lp  = g * 16 + v / wdt;
  const int tc  = g + v % wdt;
  const int l = lp * 2;
  const int t = tc * 32 + tl;

  const size_t strE2 = (size_t)(BB * TT);  // float4 stride per d4 plane
  const float4* i2p = (const float4*)E2c + (size_t)(half * 64) * strE2 + (b * TT + t);
  const float4* q0p = (const float4*)(E1 + ((size_t)(b * LL + l)) * DD) + half * 64;
  const float4* q1p = q0p + DD / 4;
  const float4* wp  = (const float4*)wt + half * 64;

  float a00=0,a01=0,a02=0,a03=0, a10=0,a11=0,a12=0,a13=0;
#pragma unroll 4
  for (int j = 0; j < 64; ++j) {
    float4 vv = i2p[(size_t)j * strE2];
    float4 q0 = q0p[j];
    float4 q1 = q1p[j];
    float4 w  = wp[j];
    a00 = fmaf(w.x, __builtin_amdgcn_rcpf(fmaf(q0.x, vv.x, 1.0f)), a00);
    a01 = fmaf(w.y, __builtin_amdgcn_rcpf(fmaf(q0.y, vv.y, 1.0f)), a01);
    a02 = fmaf(w.z, __builtin_amdgcn_rcpf(fmaf(q0.z, vv.z, 1.0f)), a02);
    a03 = fmaf(w.w, __builtin_amdgcn_rcpf(fmaf(q0.w, vv.w, 1.0f)), a03);
    a10 = fmaf(w.x, __builtin_amdgcn_rcpf(fmaf(q1.x, vv.x, 1.0f)), a10);
    a11 = fmaf(w.y, __builtin_amdgcn_rcpf(fmaf(q1.y, vv.y, 1.0f)), a11);
    a12 = fmaf(w.z, __builtin_amdgcn_rcpf(fmaf(q1.z, vv.z, 1.0f)), a12);
    a13 = fmaf(w.w, __builtin_amdgcn_rcpf(fmaf(q1.w, vv.w, 1.0f)), a13);
  }
  float s0 = (a00 + a01) + (a02 + a03);
  float s1 = (a10 + a11) + (a12 + a13);
  s0 += __shfl_xor(s0, 32);
  s1 += __shfl_xor(s1, 32);
  if (lane < 32) {
    float* sp = Sg + ((size_t)(b * LL + l)) * TT + t;
    sp[0]  = s0;
    sp[TT] = s1;
  }
}

// ---------------------------------------------------------------------------
// Kernel 3: softmax + PV. Block = (b, 2 rows) -> 512 blocks = 2/CU.
// Applies triangle + memory mask here (unwritten Sg tiles are select-
// discarded before any arithmetic).
// ---------------------------------------------------------------------------
__global__ __launch_bounds__(256) void softmax_pv(
    const float* __restrict__ Sg, const float* __restrict__ mem,
    const int* __restrict__ mask, float* __restrict__ out)
{
  const int l0 = blockIdx.x * 2;
  const int b  = blockIdx.y;
  const int tid  = threadIdx.x;
  const int lane = tid & 63;
  const int r    = tid >> 6;

  __shared__ __align__(8) float P[TT][2];
  __shared__ float rinvS[2];

  if (r < 2) {
    const int l = l0 + r;
    const float* srow = Sg + ((size_t)(b * LL + l)) * TT;
    const int tb = lane * 4;
    float4 h = *(const float4*)(srow + tb);
    const int4 mk = *(const int4*)(mask + b * TT + tb);
    float v0 = (tb + 0 >= l && mk.x != 0) ? -2.0f * h.x : -1e30f;
    float v1 = (tb + 1 >= l && mk.y != 0) ? -2.0f * h.y : -1e30f;
    float v2 = (tb + 2 >= l && mk.z != 0) ? -2.0f * h.z : -1e30f;
    float v3 = (tb + 3 >= l && mk.w != 0) ? -2.0f * h.w : -1e30f;
    float mx = fmaxf(fmaxf(v0, v1), fmaxf(v2, v3));
#pragma unroll
    for (int o = 1; o < 64; o <<= 1) mx = fmaxf(mx, __shfl_xor(mx, o));
    float e0 = __expf(v0 - mx), e1 = __expf(v1 - mx),
          e2 = __expf(v2 - mx), e3 = __expf(v3 - mx);
    P[tb + 0][r] = e0; P[tb + 1][r] = e1;
    P[tb + 2][r] = e2; P[tb + 3][r] = e3;
    float sm = (e0 + e1) + (e2 + e3);
#pragma unroll
    for (int o = 1; o < 64; o <<= 1) sm += __shfl_xor(sm, o);
    if (lane == 0) rinvS[r] = 1.0f / sm;
  }
  __syncthreads();

  const int dd = tid * 2;
  const float* mp = mem + ((size_t)b * TT) * DD + dd;
  float ax0 = 0, ay0 = 0, ax1 = 0, ay1 = 0;
#pragma unroll 4
  for (int t = l0; t < TT; ++t) {
    float2 p  = *(const float2*)(&P[t][0]);      // broadcast read
    float2 mv = *(const float2*)(mp + (size_t)t * DD);
    ax0 = fmaf(p.x, mv.x, ax0); ay0 = fmaf(p.x, mv.y, ay0);
    ax1 = fmaf(p.y, mv.x, ax1); ay1 = fmaf(p.y, mv.y, ay1);
  }
  const float r0 = rinvS[0], r1 = rinvS[1];
  float* op = out + ((size_t)(b * LL + l0)) * DD + dd;
  float2 o0 = {ax0 * r0, ay0 * r0}; *(float2*)(op)      = o0;
  float2 o1 = {ax1 * r1, ay1 * r1}; *(float2*)(op + DD) = o1;
}

extern "C" void kernel_launch(void* const* d_in, const int* in_sizes, int n_in,
                              void* d_out, int out_size, void* d_ws, size_t ws_size,
                              hipStream_t stream) {
  const float* x   = (const float*)d_in[0];
  const float* mem = (const float*)d_in[1];
  const float* W1  = (const float*)d_in[2];
  const float* b1  = (const float*)d_in[3];
  const float* W2  = (const float*)d_in[4];
  const float* b2  = (const float*)d_in[5];
  const float* wt  = (const float*)d_in[6];
  const int* mask  = (const int*)d_in[8];
  float* outp = (float*)d_out;

  float* E1  = (float*)d_ws;                     // [B*L, D]        2 MB
  float* E2c = E1 + (size_t)BB * LL * DD;        // [D/4][B*T][4]   2 MB
  float* Sg  = E2c + (size_t)BB * TT * DD;       // [B][L][T]       1 MB  (5 MB total)

  proj_gemm<<<dim3((BB * LL + BB * TT) / 32, DD / 64), 256, 0, stream>>>(
      x, mem, W1, b1, W2, b2, E1, E2c);
  score_kernel<<<576, 256, 0, stream>>>(E1, E2c, wt, Sg);
  softmax_pv<<<dim3(LL / 2, BB), 256, 0, stream>>>(Sg, mem, mask, outp);
}

// Round 5
// 60.659 us; speedup vs baseline: 1.8292x; 1.3374x over previous
//
#include <hip/hip_runtime.h>
#include <math.h>

#define BB 4
#define LL 256
#define TT 256
#define DD 512

// e^{2x} = exp2(x * 2/ln2)
#define EXP2K 2.885390081777927f

using short8 = __attribute__((ext_vector_type(8))) short;
using f32x4  = __attribute__((ext_vector_type(4))) float;

__device__ __forceinline__ unsigned cvt2bf(float a, float b) {
  unsigned r;
  asm("v_cvt_pk_bf16_f32 %0, %1, %2" : "=v"(r) : "v"(a), "v"(b));
  return r;  // lo = bf16(a), hi = bf16(b)
}

// ---------------------------------------------------------------------------
// Kernel 1: combined projection GEMM via bf16 MFMA, fp32 accumulate.
// Rows 0..1023:   E1 = exp(2*(x@W1^T+b1))   row-major [B*L, D]
// Rows 1024..2047: E2c = exp(2*(mem@W2^T+b2)) CHUNKED [d>>2][b*T+t][d&3]
// Tile 32(M)x64(N), BK=64, 256 thr = 4 waves (wave: 16 rows x 32 cols).
// A and W staged to LDS as bf16, rows padded to 144 B so ds_read_b128 frag
// reads rotate over all 8 bank-sets (2-way max = free).
// ---------------------------------------------------------------------------
__global__ __launch_bounds__(256) void proj_gemm(
    const float* __restrict__ x, const float* __restrict__ mem,
    const float* __restrict__ W1, const float* __restrict__ b1,
    const float* __restrict__ W2, const float* __restrict__ b2,
    float* __restrict__ E1, float* __restrict__ E2c)
{
  __shared__ __align__(16) char Abuf[32 * 144];   // 32 rows x 64 bf16 (+pad)
  __shared__ __align__(16) char Bbuf[64 * 144];   // 64 cols x 64 bf16 (+pad)

  const int tid = threadIdx.x;
  const int m0 = blockIdx.x * 32;      // 0..2047 in steps of 32
  const int n0 = blockIdx.y * 64;      // 0..511  in steps of 64
  const bool second = (m0 >= BB * LL);

  const float* A    = second ? mem + (size_t)(m0 - BB * LL) * DD
                             : x   + (size_t)m0 * DD;
  const float* W    = second ? W2 : W1;
  const float* bias = second ? b2 : b1;

  const int srow = tid >> 4;           // 0..15 staging row
  const int kq   = (tid & 15) * 4;     // k quad within 64

  const int lane = tid & 63;
  const int wid  = tid >> 6;
  const int r0   = (wid & 1) * 16;     // wave row strip
  const int n0w  = (wid >> 1) * 32;    // wave col strip
  const int lr   = lane & 15;
  const int lg   = lane >> 4;

  const int aoff = (r0 + lr) * 144 + lg * 16;
  const int boff0 = (n0w + lr) * 144 + lg * 16;
  const int boff1 = (n0w + 16 + lr) * 144 + lg * 16;

  f32x4 acc0 = {0.f, 0.f, 0.f, 0.f};
  f32x4 acc1 = {0.f, 0.f, 0.f, 0.f};

  for (int kc = 0; kc < DD; kc += 64) {
    __syncthreads();   // previous iteration's frag reads done
#pragma unroll
    for (int p = 0; p < 2; ++p) {      // A: 32 rows
      const int r = srow + p * 16;
      float4 v = *(const float4*)(A + (size_t)r * DD + kc + kq);
      uint2 u = {cvt2bf(v.x, v.y), cvt2bf(v.z, v.w)};
      *(uint2*)(Abuf + r * 144 + kq * 2) = u;
    }
#pragma unroll
    for (int p = 0; p < 4; ++p) {      // B: 64 rows (= n cols)
      const int r = srow + p * 16;
      float4 v = *(const float4*)(W + (size_t)(n0 + r) * DD + kc + kq);
      uint2 u = {cvt2bf(v.x, v.y), cvt2bf(v.z, v.w)};
      *(uint2*)(Bbuf + r * 144 + kq * 2) = u;
    }
    __syncthreads();
#pragma unroll
    for (int ks = 0; ks < 2; ++ks) {
      short8 af  = *(const short8*)(Abuf + aoff  + ks * 64);
      short8 bf0 = *(const short8*)(Bbuf + boff0 + ks * 64);
      short8 bf1 = *(const short8*)(Bbuf + boff1 + ks * 64);
      acc0 = __builtin_amdgcn_mfma_f32_16x16x32_bf16(af, bf0, acc0, 0, 0, 0);
      acc1 = __builtin_amdgcn_mfma_f32_16x16x32_bf16(af, bf1, acc1, 0, 0, 0);
    }
  }

  // epilogue: C layout col=lane&15, row=(lane>>4)*4+i
#pragma unroll
  for (int nf = 0; nf < 2; ++nf) {
    const f32x4 a = nf ? acc1 : acc0;
    const int col = n0 + n0w + nf * 16 + lr;
    const float bv = bias[col];
#pragma unroll
    for (int i = 0; i < 4; ++i) {
      const int mrow = m0 + r0 + lg * 4 + i;   // global combined row
      const float val = exp2f((a[i] + bv) * EXP2K);
      if (!second) {
        E1[(size_t)mrow * DD + col] = val;
      } else {
        const int m2 = mrow - BB * LL;
        E2c[((size_t)(col >> 2) * (BB * TT) + m2) * 4 + (col & 3)] = val;
      }
    }
  }
}

// ---------------------------------------------------------------------------
// Kernel 2: scores via exp-product trick.
//   tanh(q+v) = 1 - 2/(Eq*Ev+1);  S = const - 2*sum_d w_d/(Eq*Ev+1)
// (const drops out of softmax -> store sum w*r only).
// One wave per (b, l-PAIR, 32-wide t-tile): lanes 0..31 cover d[0:256) for
// 32 t values, lanes 32..63 cover d[256:512); one shfl_xor(32) combines.
// Exact task map: 576 tasks/b, 2304 equal waves. Sg [B][L][T] (1 MB).
// ---------------------------------------------------------------------------
__global__ __launch_bounds__(256) void score_kernel(
    const float* __restrict__ E1, const float* __restrict__ E2c,
    const float* __restrict__ wt, float* __restrict__ Sg)
{
  const int tid  = threadIdx.x;
  const int lane = tid & 63;
  const int tl   = lane & 31;
  const int half = lane >> 5;
  const int wid  = blockIdx.x * 4 + (tid >> 6);   // 0..2303
  const int b = wid / 576;
  const int u = wid - b * 576;
  // cumulative task count before group g: C(g) = 8*g*(17-g)
  int g;
  if (u < 240)      g = (u < 128) ? 0 : 1;
  else if (u < 416) g = (u < 336) ? 2 : 3;
  else if (u < 528) g = (u < 480) ? 4 : 5;
  else              g = (u < 560) ? 6 : 7;
  const int v   = u - 8 * g * (17 - g);
  const int wdt = 8 - g;                  // tiles per l-pair in this group
  const int lp  = g * 16 + v / wdt;
  const int tc  = g + v % wdt;
  const int l = lp * 2;
  const int t = tc * 32 + tl;

  const size_t strE2 = (size_t)(BB * TT);  // float4 stride per d4 plane
  const float4* i2p = (const float4*)E2c + (size_t)(half * 64) * strE2 + (b * TT + t);
  const float4* q0p = (const float4*)(E1 + ((size_t)(b * LL + l)) * DD) + half * 64;
  const float4* q1p = q0p + DD / 4;
  const float4* wp  = (const float4*)wt + half * 64;

  float a00=0,a01=0,a02=0,a03=0, a10=0,a11=0,a12=0,a13=0;
#pragma unroll 4
  for (int j = 0; j < 64; ++j) {
    float4 vv = i2p[(size_t)j * strE2];
    float4 q0 = q0p[j];
    float4 q1 = q1p[j];
    float4 w  = wp[j];
    a00 = fmaf(w.x, __builtin_amdgcn_rcpf(fmaf(q0.x, vv.x, 1.0f)), a00);
    a01 = fmaf(w.y, __builtin_amdgcn_rcpf(fmaf(q0.y, vv.y, 1.0f)), a01);
    a02 = fmaf(w.z, __builtin_amdgcn_rcpf(fmaf(q0.z, vv.z, 1.0f)), a02);
    a03 = fmaf(w.w, __builtin_amdgcn_rcpf(fmaf(q0.w, vv.w, 1.0f)), a03);
    a10 = fmaf(w.x, __builtin_amdgcn_rcpf(fmaf(q1.x, vv.x, 1.0f)), a10);
    a11 = fmaf(w.y, __builtin_amdgcn_rcpf(fmaf(q1.y, vv.y, 1.0f)), a11);
    a12 = fmaf(w.z, __builtin_amdgcn_rcpf(fmaf(q1.z, vv.z, 1.0f)), a12);
    a13 = fmaf(w.w, __builtin_amdgcn_rcpf(fmaf(q1.w, vv.w, 1.0f)), a13);
  }
  float s0 = (a00 + a01) + (a02 + a03);
  float s1 = (a10 + a11) + (a12 + a13);
  s0 += __shfl_xor(s0, 32);
  s1 += __shfl_xor(s1, 32);
  if (lane < 32) {
    float* sp = Sg + ((size_t)(b * LL + l)) * TT + t;
    sp[0]  = s0;
    sp[TT] = s1;
  }
}

// ---------------------------------------------------------------------------
// Kernel 3: softmax + PV. Block = (b, 2 rows, d-half) -> 1024 blocks = 4/CU,
// 128 threads. Softmax (2 waves, one row each) duplicated across the 2
// d-half blocks (cheap); PV covers 256 d columns per block.
// Triangle + memory mask applied here.
// ---------------------------------------------------------------------------
__global__ __launch_bounds__(128) void softmax_pv(
    const float* __restrict__ Sg, const float* __restrict__ mem,
    const int* __restrict__ mask, float* __restrict__ out)
{
  const int l0 = blockIdx.x * 2;
  const int b  = blockIdx.y;
  const int half = blockIdx.z;
  const int tid  = threadIdx.x;          // 0..127
  const int lane = tid & 63;
  const int r    = tid >> 6;             // 0..1

  __shared__ __align__(8) float P[TT][2];
  __shared__ float rinvS[2];

  {
    const int l = l0 + r;
    const float* srow = Sg + ((size_t)(b * LL + l)) * TT;
    const int tb = lane * 4;
    float4 h = *(const float4*)(srow + tb);
    const int4 mk = *(const int4*)(mask + b * TT + tb);
    float v0 = (tb + 0 >= l && mk.x != 0) ? -2.0f * h.x : -1e30f;
    float v1 = (tb + 1 >= l && mk.y != 0) ? -2.0f * h.y : -1e30f;
    float v2 = (tb + 2 >= l && mk.z != 0) ? -2.0f * h.z : -1e30f;
    float v3 = (tb + 3 >= l && mk.w != 0) ? -2.0f * h.w : -1e30f;
    float mx = fmaxf(fmaxf(v0, v1), fmaxf(v2, v3));
#pragma unroll
    for (int o = 1; o < 64; o <<= 1) mx = fmaxf(mx, __shfl_xor(mx, o));
    float e0 = __expf(v0 - mx), e1 = __expf(v1 - mx),
          e2 = __expf(v2 - mx), e3 = __expf(v3 - mx);
    P[tb + 0][r] = e0; P[tb + 1][r] = e1;
    P[tb + 2][r] = e2; P[tb + 3][r] = e3;
    float sm = (e0 + e1) + (e2 + e3);
#pragma unroll
    for (int o = 1; o < 64; o <<= 1) sm += __shfl_xor(sm, o);
    if (lane == 0) rinvS[r] = 1.0f / sm;
  }
  __syncthreads();

  const int dd = half * 256 + tid * 2;
  const float* mp = mem + ((size_t)b * TT) * DD + dd;
  float ax0 = 0, ay0 = 0, ax1 = 0, ay1 = 0;
#pragma unroll 4
  for (int t = l0; t < TT; ++t) {
    float2 p  = *(const float2*)(&P[t][0]);      // broadcast read
    float2 mv = *(const float2*)(mp + (size_t)t * DD);
    ax0 = fmaf(p.x, mv.x, ax0); ay0 = fmaf(p.x, mv.y, ay0);
    ax1 = fmaf(p.y, mv.x, ax1); ay1 = fmaf(p.y, mv.y, ay1);
  }
  const float r0 = rinvS[0], r1 = rinvS[1];
  float* op = out + ((size_t)(b * LL + l0)) * DD + dd;
  float2 o0 = {ax0 * r0, ay0 * r0}; *(float2*)(op)      = o0;
  float2 o1 = {ax1 * r1, ay1 * r1}; *(float2*)(op + DD) = o1;
}

extern "C" void kernel_launch(void* const* d_in, const int* in_sizes, int n_in,
                              void* d_out, int out_size, void* d_ws, size_t ws_size,
                              hipStream_t stream) {
  const float* x   = (const float*)d_in[0];
  const float* mem = (const float*)d_in[1];
  const float* W1  = (const float*)d_in[2];
  const float* b1  = (const float*)d_in[3];
  const float* W2  = (const float*)d_in[4];
  const float* b2  = (const float*)d_in[5];
  const float* wt  = (const float*)d_in[6];
  const int* mask  = (const int*)d_in[8];
  float* outp = (float*)d_out;

  float* E1  = (float*)d_ws;                     // [B*L, D]        2 MB
  float* E2c = E1 + (size_t)BB * LL * DD;        // [D/4][B*T][4]   2 MB
  float* Sg  = E2c + (size_t)BB * TT * DD;       // [B][L][T]       1 MB  (5 MB total)

  proj_gemm<<<dim3((BB * LL + BB * TT) / 32, DD / 64), 256, 0, stream>>>(
      x, mem, W1, b1, W2, b2, E1, E2c);
  score_kernel<<<576, 256, 0, stream>>>(E1, E2c, wt, Sg);
  softmax_pv<<<dim3(LL / 2, BB, 2), 128, 0, stream>>>(Sg, mem, mask, outp);
}

// Round 6
// 52.453 us; speedup vs baseline: 2.1154x; 1.1565x over previous
//
#include <hip/hip_runtime.h>
#include <math.h>

#define BB 4
#define LL 256
#define TT 256
#define DD 512

// e^{2x} = exp2(x * 2/ln2)
#define EXP2K 2.885390081777927f

using short8 = __attribute__((ext_vector_type(8))) short;
using f32x4  = __attribute__((ext_vector_type(4))) float;

__device__ __forceinline__ unsigned cvt2bf(float a, float b) {
  unsigned r;
  asm("v_cvt_pk_bf16_f32 %0, %1, %2" : "=v"(r) : "v"(a), "v"(b));
  return r;  // lo = bf16(a), hi = bf16(b)
}

// ---------------------------------------------------------------------------
// Kernel 1: combined projection GEMM via bf16 MFMA, fp32 accumulate.
// Rows 0..1023:   E1 = exp(2*(x@W1^T+b1))   row-major [B*L, D]
// Rows 1024..2047: E2c = exp(2*(mem@W2^T+b2)) CHUNKED [d>>2][b*T+t][d&3]
// Tile 32(M)x64(N), BK=64, 256 thr = 4 waves (wave: 16 rows x 32 cols).
// A and W staged to LDS as bf16, rows padded to 144 B so ds_read_b128 frag
// reads rotate over all 8 bank-sets (2-way max = free).
// ---------------------------------------------------------------------------
__global__ __launch_bounds__(256) void proj_gemm(
    const float* __restrict__ x, const float* __restrict__ mem,
    const float* __restrict__ W1, const float* __restrict__ b1,
    const float* __restrict__ W2, const float* __restrict__ b2,
    float* __restrict__ E1, float* __restrict__ E2c)
{
  __shared__ __align__(16) char Abuf[32 * 144];   // 32 rows x 64 bf16 (+pad)
  __shared__ __align__(16) char Bbuf[64 * 144];   // 64 cols x 64 bf16 (+pad)

  const int tid = threadIdx.x;
  const int m0 = blockIdx.x * 32;      // 0..2047 in steps of 32
  const int n0 = blockIdx.y * 64;      // 0..511  in steps of 64
  const bool second = (m0 >= BB * LL);

  const float* A    = second ? mem + (size_t)(m0 - BB * LL) * DD
                             : x   + (size_t)m0 * DD;
  const float* W    = second ? W2 : W1;
  const float* bias = second ? b2 : b1;

  const int srow = tid >> 4;           // 0..15 staging row
  const int kq   = (tid & 15) * 4;     // k quad within 64

  const int lane = tid & 63;
  const int wid  = tid >> 6;
  const int r0   = (wid & 1) * 16;     // wave row strip
  const int n0w  = (wid >> 1) * 32;    // wave col strip
  const int lr   = lane & 15;
  const int lg   = lane >> 4;

  const int aoff = (r0 + lr) * 144 + lg * 16;
  const int boff0 = (n0w + lr) * 144 + lg * 16;
  const int boff1 = (n0w + 16 + lr) * 144 + lg * 16;

  f32x4 acc0 = {0.f, 0.f, 0.f, 0.f};
  f32x4 acc1 = {0.f, 0.f, 0.f, 0.f};

  for (int kc = 0; kc < DD; kc += 64) {
    __syncthreads();   // previous iteration's frag reads done
#pragma unroll
    for (int p = 0; p < 2; ++p) {      // A: 32 rows
      const int r = srow + p * 16;
      float4 v = *(const float4*)(A + (size_t)r * DD + kc + kq);
      uint2 u = {cvt2bf(v.x, v.y), cvt2bf(v.z, v.w)};
      *(uint2*)(Abuf + r * 144 + kq * 2) = u;
    }
#pragma unroll
    for (int p = 0; p < 4; ++p) {      // B: 64 rows (= n cols)
      const int r = srow + p * 16;
      float4 v = *(const float4*)(W + (size_t)(n0 + r) * DD + kc + kq);
      uint2 u = {cvt2bf(v.x, v.y), cvt2bf(v.z, v.w)};
      *(uint2*)(Bbuf + r * 144 + kq * 2) = u;
    }
    __syncthreads();
#pragma unroll
    for (int ks = 0; ks < 2; ++ks) {
      short8 af  = *(const short8*)(Abuf + aoff  + ks * 64);
      short8 bf0 = *(const short8*)(Bbuf + boff0 + ks * 64);
      short8 bf1 = *(const short8*)(Bbuf + boff1 + ks * 64);
      acc0 = __builtin_amdgcn_mfma_f32_16x16x32_bf16(af, bf0, acc0, 0, 0, 0);
      acc1 = __builtin_amdgcn_mfma_f32_16x16x32_bf16(af, bf1, acc1, 0, 0, 0);
    }
  }

  // epilogue: C layout col=lane&15, row=(lane>>4)*4+i
#pragma unroll
  for (int nf = 0; nf < 2; ++nf) {
    const f32x4 a = nf ? acc1 : acc0;
    const int col = n0 + n0w + nf * 16 + lr;
    const float bv = bias[col];
#pragma unroll
    for (int i = 0; i < 4; ++i) {
      const int mrow = m0 + r0 + lg * 4 + i;   // global combined row
      const float val = exp2f((a[i] + bv) * EXP2K);
      if (!second) {
        E1[(size_t)mrow * DD + col] = val;
      } else {
        const int m2 = mrow - BB * LL;
        E2c[((size_t)(col >> 2) * (BB * TT) + m2) * 4 + (col & 3)] = val;
      }
    }
  }
}

// ---------------------------------------------------------------------------
// Kernel 2: scores via exp-product trick.
//   tanh(q+v) = 1 - 2/(Eq*Ev+1);  S = const - 2*sum_d w_d/(Eq*Ev+1)
// (const drops out of softmax -> store sum w*r only).
// One wave per (b, l-PAIR, 16-wide t-tile): lane = (d-quarter tq, t-lane tl).
// Lane covers d in [tq*128,(tq+1)*128) for t = tc*16+tl; combine via
// shfl_xor(16)+shfl_xor(32). Exact triangle task map: group g = lp>>3,
// tiles tc in [g,16) -> C(g)=4g(33-g), 1088 tasks/b, 4352 equal waves
// (4.25/SIMD for latency hiding -- R5's 2304 waves were latency-bound).
// ---------------------------------------------------------------------------
__global__ __launch_bounds__(256) void score_kernel(
    const float* __restrict__ E1, const float* __restrict__ E2c,
    const float* __restrict__ wt, float* __restrict__ Sg)
{
  const int tid  = threadIdx.x;
  const int lane = tid & 63;
  const int tl   = lane & 15;
  const int tq   = lane >> 4;                     // d-quarter
  const int wid  = blockIdx.x * 4 + (tid >> 6);   // 0..4351
  const int b = wid / 1088;
  const int u = wid - b * 1088;
  // cumulative task count before group g: C(g) = 4*g*(33-g)
  int g;
  if (u < 464)       g = (u < 248) ? ((u < 128) ? 0 : 1) : ((u < 360) ? 2 : 3);
  else if (u < 800)  g = (u < 648) ? ((u < 560) ? 4 : 5) : ((u < 728) ? 6 : 7);
  else if (u < 1008) g = (u < 920) ? ((u < 864) ? 8 : 9) : ((u < 968) ? 10 : 11);
  else               g = (u < 1064) ? ((u < 1040) ? 12 : 13) : ((u < 1080) ? 14 : 15);
  const int v   = u - 4 * g * (33 - g);
  const int wdt = 16 - g;                 // tiles per l-pair in this group
  const int lp  = g * 8 + v / wdt;
  const int tc  = g + v % wdt;
  const int l = lp * 2;
  const int t = tc * 16 + tl;

  const size_t strE2 = (size_t)(BB * TT);  // float4 stride per d4 plane
  const float4* i2p = (const float4*)E2c + (size_t)(tq * 32) * strE2 + (b * TT + t);
  const float4* q0p = (const float4*)(E1 + ((size_t)(b * LL + l)) * DD) + tq * 32;
  const float4* q1p = q0p + DD / 4;
  const float4* wp  = (const float4*)wt + tq * 32;

  float a00=0,a01=0,a02=0,a03=0, a10=0,a11=0,a12=0,a13=0;
#pragma unroll 4
  for (int j = 0; j < 32; ++j) {
    float4 vv = i2p[(size_t)j * strE2];
    float4 q0 = q0p[j];
    float4 q1 = q1p[j];
    float4 w  = wp[j];
    a00 = fmaf(w.x, __builtin_amdgcn_rcpf(fmaf(q0.x, vv.x, 1.0f)), a00);
    a01 = fmaf(w.y, __builtin_amdgcn_rcpf(fmaf(q0.y, vv.y, 1.0f)), a01);
    a02 = fmaf(w.z, __builtin_amdgcn_rcpf(fmaf(q0.z, vv.z, 1.0f)), a02);
    a03 = fmaf(w.w, __builtin_amdgcn_rcpf(fmaf(q0.w, vv.w, 1.0f)), a03);
    a10 = fmaf(w.x, __builtin_amdgcn_rcpf(fmaf(q1.x, vv.x, 1.0f)), a10);
    a11 = fmaf(w.y, __builtin_amdgcn_rcpf(fmaf(q1.y, vv.y, 1.0f)), a11);
    a12 = fmaf(w.z, __builtin_amdgcn_rcpf(fmaf(q1.z, vv.z, 1.0f)), a12);
    a13 = fmaf(w.w, __builtin_amdgcn_rcpf(fmaf(q1.w, vv.w, 1.0f)), a13);
  }
  float s0 = (a00 + a01) + (a02 + a03);
  float s1 = (a10 + a11) + (a12 + a13);
  s0 += __shfl_xor(s0, 16);
  s0 += __shfl_xor(s0, 32);
  s1 += __shfl_xor(s1, 16);
  s1 += __shfl_xor(s1, 32);
  if (lane < 16) {
    float* sp = Sg + ((size_t)(b * LL + l)) * TT + t;
    sp[0]  = s0;
    sp[TT] = s1;
  }
}

// ---------------------------------------------------------------------------
// Kernel 3: softmax + PV. Block = (b, 2 rows, d-half) -> 1024 blocks = 4/CU,
// 128 threads. Softmax (2 waves, one row each) duplicated across the 2
// d-half blocks (cheap); PV covers 256 d columns per block.
// Triangle + memory mask applied here (unwritten Sg tiles select-discarded).
// ---------------------------------------------------------------------------
__global__ __launch_bounds__(128) void softmax_pv(
    const float* __restrict__ Sg, const float* __restrict__ mem,
    const int* __restrict__ mask, float* __restrict__ out)
{
  const int l0 = blockIdx.x * 2;
  const int b  = blockIdx.y;
  const int half = blockIdx.z;
  const int tid  = threadIdx.x;          // 0..127
  const int lane = tid & 63;
  const int r    = tid >> 6;             // 0..1

  __shared__ __align__(8) float P[TT][2];
  __shared__ float rinvS[2];

  {
    const int l = l0 + r;
    const float* srow = Sg + ((size_t)(b * LL + l)) * TT;
    const int tb = lane * 4;
    float4 h = *(const float4*)(srow + tb);
    const int4 mk = *(const int4*)(mask + b * TT + tb);
    float v0 = (tb + 0 >= l && mk.x != 0) ? -2.0f * h.x : -1e30f;
    float v1 = (tb + 1 >= l && mk.y != 0) ? -2.0f * h.y : -1e30f;
    float v2 = (tb + 2 >= l && mk.z != 0) ? -2.0f * h.z : -1e30f;
    float v3 = (tb + 3 >= l && mk.w != 0) ? -2.0f * h.w : -1e30f;
    float mx = fmaxf(fmaxf(v0, v1), fmaxf(v2, v3));
#pragma unroll
    for (int o = 1; o < 64; o <<= 1) mx = fmaxf(mx, __shfl_xor(mx, o));
    float e0 = __expf(v0 - mx), e1 = __expf(v1 - mx),
          e2 = __expf(v2 - mx), e3 = __expf(v3 - mx);
    P[tb + 0][r] = e0; P[tb + 1][r] = e1;
    P[tb + 2][r] = e2; P[tb + 3][r] = e3;
    float sm = (e0 + e1) + (e2 + e3);
#pragma unroll
    for (int o = 1; o < 64; o <<= 1) sm += __shfl_xor(sm, o);
    if (lane == 0) rinvS[r] = 1.0f / sm;
  }
  __syncthreads();

  const int dd = half * 256 + tid * 2;
  const float* mp = mem + ((size_t)b * TT) * DD + dd;
  float ax0 = 0, ay0 = 0, ax1 = 0, ay1 = 0;
#pragma unroll 4
  for (int t = l0; t < TT; ++t) {
    float2 p  = *(const float2*)(&P[t][0]);      // broadcast read
    float2 mv = *(const float2*)(mp + (size_t)t * DD);
    ax0 = fmaf(p.x, mv.x, ax0); ay0 = fmaf(p.x, mv.y, ay0);
    ax1 = fmaf(p.y, mv.x, ax1); ay1 = fmaf(p.y, mv.y, ay1);
  }
  const float r0 = rinvS[0], r1 = rinvS[1];
  float* op = out + ((size_t)(b * LL + l0)) * DD + dd;
  float2 o0 = {ax0 * r0, ay0 * r0}; *(float2*)(op)      = o0;
  float2 o1 = {ax1 * r1, ay1 * r1}; *(float2*)(op + DD) = o1;
}

extern "C" void kernel_launch(void* const* d_in, const int* in_sizes, int n_in,
                              void* d_out, int out_size, void* d_ws, size_t ws_size,
                              hipStream_t stream) {
  const float* x   = (const float*)d_in[0];
  const float* mem = (const float*)d_in[1];
  const float* W1  = (const float*)d_in[2];
  const float* b1  = (const float*)d_in[3];
  const float* W2  = (const float*)d_in[4];
  const float* b2  = (const float*)d_in[5];
  const float* wt  = (const float*)d_in[6];
  const int* mask  = (const int*)d_in[8];
  float* outp = (float*)d_out;

  float* E1  = (float*)d_ws;                     // [B*L, D]        2 MB
  float* E2c = E1 + (size_t)BB * LL * DD;        // [D/4][B*T][4]   2 MB
  float* Sg  = E2c + (size_t)BB * TT * DD;       // [B][L][T]       1 MB  (5 MB total)

  proj_gemm<<<dim3((BB * LL + BB * TT) / 32, DD / 64), 256, 0, stream>>>(
      x, mem, W1, b1, W2, b2, E1, E2c);
  score_kernel<<<1088, 256, 0, stream>>>(E1, E2c, wt, Sg);
  softmax_pv<<<dim3(LL / 2, BB, 2), 128, 0, stream>>>(Sg, mem, mask, outp);
}

// Round 7
// 47.941 us; speedup vs baseline: 2.3145x; 1.0941x over previous
//
#include <hip/hip_runtime.h>
#include <math.h>

#define BB 4
#define LL 256
#define TT 256
#define DD 512

// e^{2x} = exp2(x * 2/ln2)
#define EXP2K 2.885390081777927f

using short8 = __attribute__((ext_vector_type(8))) short;
using f32x4  = __attribute__((ext_vector_type(4))) float;

__device__ __forceinline__ unsigned cvt2bf(float a, float b) {
  unsigned r;
  asm("v_cvt_pk_bf16_f32 %0, %1, %2" : "=v"(r) : "v"(a), "v"(b));
  return r;  // lo = bf16(a), hi = bf16(b)
}

// ---------------------------------------------------------------------------
// Kernel 1: combined projection GEMM via bf16 MFMA, fp32 accumulate.
// Rows 0..1023:   E1 = exp(2*(x@W1^T+b1))   row-major [B*L, D]
// Rows 1024..2047: E2c = exp(2*(mem@W2^T+b2)) CHUNKED [d>>2][b*T+t][d&3]
// ---------------------------------------------------------------------------
__global__ __launch_bounds__(256) void proj_gemm(
    const float* __restrict__ x, const float* __restrict__ mem,
    const float* __restrict__ W1, const float* __restrict__ b1,
    const float* __restrict__ W2, const float* __restrict__ b2,
    float* __restrict__ E1, float* __restrict__ E2c)
{
  __shared__ __align__(16) char Abuf[32 * 144];   // 32 rows x 64 bf16 (+pad)
  __shared__ __align__(16) char Bbuf[64 * 144];   // 64 cols x 64 bf16 (+pad)

  const int tid = threadIdx.x;
  const int m0 = blockIdx.x * 32;      // 0..2047 in steps of 32
  const int n0 = blockIdx.y * 64;      // 0..511  in steps of 64
  const bool second = (m0 >= BB * LL);

  const float* A    = second ? mem + (size_t)(m0 - BB * LL) * DD
                             : x   + (size_t)m0 * DD;
  const float* W    = second ? W2 : W1;
  const float* bias = second ? b2 : b1;

  const int srow = tid >> 4;           // 0..15 staging row
  const int kq   = (tid & 15) * 4;     // k quad within 64

  const int lane = tid & 63;
  const int wid  = tid >> 6;
  const int r0   = (wid & 1) * 16;     // wave row strip
  const int n0w  = (wid >> 1) * 32;    // wave col strip
  const int lr   = lane & 15;
  const int lg   = lane >> 4;

  const int aoff = (r0 + lr) * 144 + lg * 16;
  const int boff0 = (n0w + lr) * 144 + lg * 16;
  const int boff1 = (n0w + 16 + lr) * 144 + lg * 16;

  f32x4 acc0 = {0.f, 0.f, 0.f, 0.f};
  f32x4 acc1 = {0.f, 0.f, 0.f, 0.f};

  for (int kc = 0; kc < DD; kc += 64) {
    __syncthreads();   // previous iteration's frag reads done
#pragma unroll
    for (int p = 0; p < 2; ++p) {      // A: 32 rows
      const int r = srow + p * 16;
      float4 v = *(const float4*)(A + (size_t)r * DD + kc + kq);
      uint2 u = {cvt2bf(v.x, v.y), cvt2bf(v.z, v.w)};
      *(uint2*)(Abuf + r * 144 + kq * 2) = u;
    }
#pragma unroll
    for (int p = 0; p < 4; ++p) {      // B: 64 rows (= n cols)
      const int r = srow + p * 16;
      float4 v = *(const float4*)(W + (size_t)(n0 + r) * DD + kc + kq);
      uint2 u = {cvt2bf(v.x, v.y), cvt2bf(v.z, v.w)};
      *(uint2*)(Bbuf + r * 144 + kq * 2) = u;
    }
    __syncthreads();
#pragma unroll
    for (int ks = 0; ks < 2; ++ks) {
      short8 af  = *(const short8*)(Abuf + aoff  + ks * 64);
      short8 bf0 = *(const short8*)(Bbuf + boff0 + ks * 64);
      short8 bf1 = *(const short8*)(Bbuf + boff1 + ks * 64);
      acc0 = __builtin_amdgcn_mfma_f32_16x16x32_bf16(af, bf0, acc0, 0, 0, 0);
      acc1 = __builtin_amdgcn_mfma_f32_16x16x32_bf16(af, bf1, acc1, 0, 0, 0);
    }
  }

  // epilogue: C layout col=lane&15, row=(lane>>4)*4+i
#pragma unroll
  for (int nf = 0; nf < 2; ++nf) {
    const f32x4 a = nf ? acc1 : acc0;
    const int col = n0 + n0w + nf * 16 + lr;
    const float bv = bias[col];
#pragma unroll
    for (int i = 0; i < 4; ++i) {
      const int mrow = m0 + r0 + lg * 4 + i;   // global combined row
      const float val = exp2f((a[i] + bv) * EXP2K);
      if (!second) {
        E1[(size_t)mrow * DD + col] = val;
      } else {
        const int m2 = mrow - BB * LL;
        E2c[((size_t)(col >> 2) * (BB * TT) + m2) * 4 + (col & 3)] = val;
      }
    }
  }
}

// ---------------------------------------------------------------------------
// Kernel 2: scores via exp-product trick.
//   tanh(q+v) = 1 - 2/(Eq*Ev+1);  S = const - 2*sum_d w_d/(Eq*Ev+1)
// (const drops out of softmax -> store sum w*r only).
// One BLOCK per (b, l-pair, 64-wide t-tile); its 4 waves each own a
// d-quarter (dq = readfirstlane(tid>>6) -> wave-uniform). q0/q1/w pointers
// are fully scalar -> s_load_dwordx4 broadcast on the scalar pipe; only 32
// vector loads per wave (vv, lane = t, coalesced). Cross-dq reduce via LDS.
// Exact triangle map: group g = lp>>5, tiles tc in [g,4), C = {0,128,224,288},
// 320 blocks/b -> 1280 blocks = 5/CU.
// ---------------------------------------------------------------------------
__global__ __launch_bounds__(256) void score_kernel(
    const float* __restrict__ E1, const float* __restrict__ E2c,
    const float* __restrict__ wt, float* __restrict__ Sg)
{
  __shared__ float p0[4][64];
  __shared__ float p1[4][64];

  const int tid = threadIdx.x;
  const int tl  = tid & 63;
  const int dq  = __builtin_amdgcn_readfirstlane(tid >> 6);  // wave-uniform

  const int bid = blockIdx.x;          // 0..1279
  const int b = bid / 320;
  const int u = bid - b * 320;
  int g, base;
  if (u < 224) { if (u < 128) { g = 0; base = 0; }   else { g = 1; base = 128; } }
  else         { if (u < 288) { g = 2; base = 224; } else { g = 3; base = 288; } }
  const int v   = u - base;
  const int wdt = 4 - g;
  const int lp  = g * 32 + v / wdt;
  const int tc  = g + v % wdt;
  const int l = lp * 2;
  const int t = tc * 64 + tl;

  const size_t strE2 = (size_t)(BB * TT);  // float4 stride per d4 plane
  const float4* q0p = (const float4*)(E1 + (size_t)(b * LL + l) * DD) + dq * 32;
  const float4* q1p = q0p + DD / 4;
  const float4* wp  = (const float4*)wt + dq * 32;
  const float4* vp  = (const float4*)E2c + (size_t)(dq * 32) * strE2 + (b * TT + t);

  float a00=0,a01=0,a02=0,a03=0, a10=0,a11=0,a12=0,a13=0;
#pragma unroll 8
  for (int j = 0; j < 32; ++j) {
    float4 vv = vp[(size_t)j * strE2];
    float4 q0 = q0p[j];
    float4 q1 = q1p[j];
    float4 w  = wp[j];
    a00 = fmaf(w.x, __builtin_amdgcn_rcpf(fmaf(q0.x, vv.x, 1.0f)), a00);
    a01 = fmaf(w.y, __builtin_amdgcn_rcpf(fmaf(q0.y, vv.y, 1.0f)), a01);
    a02 = fmaf(w.z, __builtin_amdgcn_rcpf(fmaf(q0.z, vv.z, 1.0f)), a02);
    a03 = fmaf(w.w, __builtin_amdgcn_rcpf(fmaf(q0.w, vv.w, 1.0f)), a03);
    a10 = fmaf(w.x, __builtin_amdgcn_rcpf(fmaf(q1.x, vv.x, 1.0f)), a10);
    a11 = fmaf(w.y, __builtin_amdgcn_rcpf(fmaf(q1.y, vv.y, 1.0f)), a11);
    a12 = fmaf(w.z, __builtin_amdgcn_rcpf(fmaf(q1.z, vv.z, 1.0f)), a12);
    a13 = fmaf(w.w, __builtin_amdgcn_rcpf(fmaf(q1.w, vv.w, 1.0f)), a13);
  }
  p0[dq][tl] = (a00 + a01) + (a02 + a03);
  p1[dq][tl] = (a10 + a11) + (a12 + a13);
  __syncthreads();

  if (tid < 128) {
    const int rr = tid >> 6;           // 0 -> row l, 1 -> row l+1
    const int tt = tid & 63;
    const float* src = rr ? &p1[0][0] : &p0[0][0];
    const float s = (src[tt] + src[64 + tt]) + (src[128 + tt] + src[192 + tt]);
    Sg[((size_t)(b * LL + l + rr)) * TT + tc * 64 + tt] = s;
  }
}

// ---------------------------------------------------------------------------
// Kernel 3: softmax + PV. Block = (b, 4 rows, d-half) -> 512 blocks, 128 thr.
// Each of the 2 waves does 2 softmax rows serially; PV covers 256 d columns,
// mem rows read once per 4 l-rows (halves L2 traffic vs 2-row blocks).
// Triangle + memory mask applied here (unwritten Sg tiles select-discarded).
// ---------------------------------------------------------------------------
__global__ __launch_bounds__(128) void softmax_pv(
    const float* __restrict__ Sg, const float* __restrict__ mem,
    const int* __restrict__ mask, float* __restrict__ out)
{
  const int l0 = blockIdx.x * 4;
  const int b  = blockIdx.y;
  const int half = blockIdx.z;
  const int tid  = threadIdx.x;          // 0..127
  const int lane = tid & 63;
  const int wv   = tid >> 6;             // 0..1

  __shared__ __align__(16) float P[TT][4];
  __shared__ float rinvS[4];

  for (int rr = wv; rr < 4; rr += 2) {
    const int l = l0 + rr;
    const float* srow = Sg + ((size_t)(b * LL + l)) * TT;
    const int tb = lane * 4;
    float4 h = *(const float4*)(srow + tb);
    const int4 mk = *(const int4*)(mask + b * TT + tb);
    float v0 = (tb + 0 >= l && mk.x != 0) ? -2.0f * h.x : -1e30f;
    float v1 = (tb + 1 >= l && mk.y != 0) ? -2.0f * h.y : -1e30f;
    float v2 = (tb + 2 >= l && mk.z != 0) ? -2.0f * h.z : -1e30f;
    float v3 = (tb + 3 >= l && mk.w != 0) ? -2.0f * h.w : -1e30f;
    float mx = fmaxf(fmaxf(v0, v1), fmaxf(v2, v3));
#pragma unroll
    for (int o = 1; o < 64; o <<= 1) mx = fmaxf(mx, __shfl_xor(mx, o));
    float e0 = __expf(v0 - mx), e1 = __expf(v1 - mx),
          e2 = __expf(v2 - mx), e3 = __expf(v3 - mx);
    P[tb + 0][rr] = e0; P[tb + 1][rr] = e1;
    P[tb + 2][rr] = e2; P[tb + 3][rr] = e3;
    float sm = (e0 + e1) + (e2 + e3);
#pragma unroll
    for (int o = 1; o < 64; o <<= 1) sm += __shfl_xor(sm, o);
    if (lane == 0) rinvS[rr] = 1.0f / sm;
  }
  __syncthreads();

  const int dd = half * 256 + tid * 2;
  const float* mp = mem + ((size_t)b * TT) * DD + dd;
  float ax0=0,ay0=0, ax1=0,ay1=0, ax2=0,ay2=0, ax3=0,ay3=0;
#pragma unroll 2
  for (int t = l0; t < TT; ++t) {
    float4 p  = *(const float4*)(&P[t][0]);      // broadcast read
    float2 mv = *(const float2*)(mp + (size_t)t * DD);
    ax0 = fmaf(p.x, mv.x, ax0); ay0 = fmaf(p.x, mv.y, ay0);
    ax1 = fmaf(p.y, mv.x, ax1); ay1 = fmaf(p.y, mv.y, ay1);
    ax2 = fmaf(p.z, mv.x, ax2); ay2 = fmaf(p.z, mv.y, ay2);
    ax3 = fmaf(p.w, mv.x, ax3); ay3 = fmaf(p.w, mv.y, ay3);
  }
  const float r0 = rinvS[0], r1 = rinvS[1], r2 = rinvS[2], r3 = rinvS[3];
  float* op = out + ((size_t)(b * LL + l0)) * DD + dd;
  float2 o0 = {ax0 * r0, ay0 * r0}; *(float2*)(op)        = o0;
  float2 o1 = {ax1 * r1, ay1 * r1}; *(float2*)(op + DD)   = o1;
  float2 o2 = {ax2 * r2, ay2 * r2}; *(float2*)(op + 2*DD) = o2;
  float2 o3 = {ax3 * r3, ay3 * r3}; *(float2*)(op + 3*DD) = o3;
}

extern "C" void kernel_launch(void* const* d_in, const int* in_sizes, int n_in,
                              void* d_out, int out_size, void* d_ws, size_t ws_size,
                              hipStream_t stream) {
  const float* x   = (const float*)d_in[0];
  const float* mem = (const float*)d_in[1];
  const float* W1  = (const float*)d_in[2];
  const float* b1  = (const float*)d_in[3];
  const float* W2  = (const float*)d_in[4];
  const float* b2  = (const float*)d_in[5];
  const float* wt  = (const float*)d_in[6];
  const int* mask  = (const int*)d_in[8];
  float* outp = (float*)d_out;

  float* E1  = (float*)d_ws;                     // [B*L, D]        2 MB
  float* E2c = E1 + (size_t)BB * LL * DD;        // [D/4][B*T][4]   2 MB
  float* Sg  = E2c + (size_t)BB * TT * DD;       // [B][L][T]       1 MB  (5 MB total)

  proj_gemm<<<dim3((BB * LL + BB * TT) / 32, DD / 64), 256, 0, stream>>>(
      x, mem, W1, b1, W2, b2, E1, E2c);
  score_kernel<<<1280, 256, 0, stream>>>(E1, E2c, wt, Sg);
  softmax_pv<<<dim3(LL / 4, BB, 2), 128, 0, stream>>>(Sg, mem, mask, outp);
}

// Round 8
// 46.773 us; speedup vs baseline: 2.3722x; 1.0250x over previous
//
#include <hip/hip_runtime.h>
#include <math.h>

#define BB 4
#define LL 256
#define TT 256
#define DD 512

// e^{2x} = exp2(x * 2/ln2)
#define EXP2K 2.885390081777927f

using short8 = __attribute__((ext_vector_type(8))) short;
using f32x4  = __attribute__((ext_vector_type(4))) float;

__device__ __forceinline__ unsigned cvt2bf(float a, float b) {
  unsigned r;
  asm("v_cvt_pk_bf16_f32 %0, %1, %2" : "=v"(r) : "v"(a), "v"(b));
  return r;  // lo = bf16(a), hi = bf16(b)
}

// ---------------------------------------------------------------------------
// Kernel 1: combined projection GEMM via bf16 MFMA, fp32 accumulate.
// Rows 0..1023:   E1 = exp(2*(x@W1^T+b1))   row-major [B*L, D]
// Rows 1024..2047: E2c = exp(2*(mem@W2^T+b2)) CHUNKED [d>>2][b*T+t][d&3]
// ---------------------------------------------------------------------------
__global__ __launch_bounds__(256) void proj_gemm(
    const float* __restrict__ x, const float* __restrict__ mem,
    const float* __restrict__ W1, const float* __restrict__ b1,
    const float* __restrict__ W2, const float* __restrict__ b2,
    float* __restrict__ E1, float* __restrict__ E2c)
{
  __shared__ __align__(16) char Abuf[32 * 144];   // 32 rows x 64 bf16 (+pad)
  __shared__ __align__(16) char Bbuf[64 * 144];   // 64 cols x 64 bf16 (+pad)

  const int tid = threadIdx.x;
  const int m0 = blockIdx.x * 32;      // 0..2047 in steps of 32
  const int n0 = blockIdx.y * 64;      // 0..511  in steps of 64
  const bool second = (m0 >= BB * LL);

  const float* A    = second ? mem + (size_t)(m0 - BB * LL) * DD
                             : x   + (size_t)m0 * DD;
  const float* W    = second ? W2 : W1;
  const float* bias = second ? b2 : b1;

  const int srow = tid >> 4;           // 0..15 staging row
  const int kq   = (tid & 15) * 4;     // k quad within 64

  const int lane = tid & 63;
  const int wid  = tid >> 6;
  const int r0   = (wid & 1) * 16;     // wave row strip
  const int n0w  = (wid >> 1) * 32;    // wave col strip
  const int lr   = lane & 15;
  const int lg   = lane >> 4;

  const int aoff = (r0 + lr) * 144 + lg * 16;
  const int boff0 = (n0w + lr) * 144 + lg * 16;
  const int boff1 = (n0w + 16 + lr) * 144 + lg * 16;

  f32x4 acc0 = {0.f, 0.f, 0.f, 0.f};
  f32x4 acc1 = {0.f, 0.f, 0.f, 0.f};

  for (int kc = 0; kc < DD; kc += 64) {
    __syncthreads();   // previous iteration's frag reads done
#pragma unroll
    for (int p = 0; p < 2; ++p) {      // A: 32 rows
      const int r = srow + p * 16;
      float4 v = *(const float4*)(A + (size_t)r * DD + kc + kq);
      uint2 u = {cvt2bf(v.x, v.y), cvt2bf(v.z, v.w)};
      *(uint2*)(Abuf + r * 144 + kq * 2) = u;
    }
#pragma unroll
    for (int p = 0; p < 4; ++p) {      // B: 64 rows (= n cols)
      const int r = srow + p * 16;
      float4 v = *(const float4*)(W + (size_t)(n0 + r) * DD + kc + kq);
      uint2 u = {cvt2bf(v.x, v.y), cvt2bf(v.z, v.w)};
      *(uint2*)(Bbuf + r * 144 + kq * 2) = u;
    }
    __syncthreads();
#pragma unroll
    for (int ks = 0; ks < 2; ++ks) {
      short8 af  = *(const short8*)(Abuf + aoff  + ks * 64);
      short8 bf0 = *(const short8*)(Bbuf + boff0 + ks * 64);
      short8 bf1 = *(const short8*)(Bbuf + boff1 + ks * 64);
      acc0 = __builtin_amdgcn_mfma_f32_16x16x32_bf16(af, bf0, acc0, 0, 0, 0);
      acc1 = __builtin_amdgcn_mfma_f32_16x16x32_bf16(af, bf1, acc1, 0, 0, 0);
    }
  }

  // epilogue: C layout col=lane&15, row=(lane>>4)*4+i
#pragma unroll
  for (int nf = 0; nf < 2; ++nf) {
    const f32x4 a = nf ? acc1 : acc0;
    const int col = n0 + n0w + nf * 16 + lr;
    const float bv = bias[col];
#pragma unroll
    for (int i = 0; i < 4; ++i) {
      const int mrow = m0 + r0 + lg * 4 + i;   // global combined row
      const float val = exp2f((a[i] + bv) * EXP2K);
      if (!second) {
        E1[(size_t)mrow * DD + col] = val;
      } else {
        const int m2 = mrow - BB * LL;
        E2c[((size_t)(col >> 2) * (BB * TT) + m2) * 4 + (col & 3)] = val;
      }
    }
  }
}

// ---------------------------------------------------------------------------
// Kernel 2: FUSED score + softmax + PV.
// Block (b, lp) owns rows r0=lp, r1=255-lp. Triangle => exactly 5 t-tiles of
// 64 per block (c0 = 4-(lp>>6) for r0, rest for r1) -- perfectly balanced.
// Score: tanh(q+v) = 1 - 2/(Eq*Ev+1); S = -2*sum w/(Eq*Ev+1) (+const dropped
// by softmax). Per tile: 4 waves x d-quarter (q/w scalar loads, 32 coalesced
// vector loads), LDS cross-dq reduce (double-buffered). Then softmax (wave 0
// -> r0, wave 1 -> r1) and PV (256 thr x 2 d-cols, loop split at r1).
// ---------------------------------------------------------------------------
__global__ __launch_bounds__(256) void fused_attn(
    const float* __restrict__ E1, const float* __restrict__ E2c,
    const float* __restrict__ wt, const float* __restrict__ mem,
    const int* __restrict__ mask, float* __restrict__ out)
{
  __shared__ float prt[2][4][64];          // (buf, dq, t-lane)
  __shared__ float S[2][TT];               // raw scores per row
  __shared__ __align__(8) float Pt[TT][2]; // probabilities, interleaved
  __shared__ float rinvS[2];

  const int tid = threadIdx.x;
  const int tl  = tid & 63;
  const int wv  = tid >> 6;
  const int dq  = __builtin_amdgcn_readfirstlane(wv);  // wave-uniform

  const int lp = blockIdx.x;        // 0..127
  const int b  = blockIdx.y;
  const int r0 = lp;
  const int r1 = 255 - lp;
  const int tc0 = r0 >> 6;
  const int tc1 = r1 >> 6;
  const int c0  = 4 - tc0;          // tiles for row0 (c0 + tiles_r1 == 5)

  const size_t strE2 = (size_t)(BB * TT);  // float4 stride per d4 plane
  const float4* wp = (const float4*)wt + dq * 32;

  // ---- score phase: 5 balanced tiles ----
  for (int it = 0; it < 5; ++it) {
    const int isr1 = (it >= c0);
    const int row  = isr1 ? r1 : r0;
    const int tc   = isr1 ? (tc1 + it - c0) : (tc0 + it);
    const int t    = tc * 64 + tl;

    const float4* qp = (const float4*)(E1 + (size_t)(b * LL + row) * DD) + dq * 32;
    const float4* vp = (const float4*)E2c + (size_t)(dq * 32) * strE2 + (b * TT + t);

    float a0 = 0.f, a1 = 0.f, a2 = 0.f, a3 = 0.f;
#pragma unroll 8
    for (int j = 0; j < 32; ++j) {
      float4 vv = vp[(size_t)j * strE2];
      float4 q  = qp[j];
      float4 w  = wp[j];
      a0 = fmaf(w.x, __builtin_amdgcn_rcpf(fmaf(q.x, vv.x, 1.0f)), a0);
      a1 = fmaf(w.y, __builtin_amdgcn_rcpf(fmaf(q.y, vv.y, 1.0f)), a1);
      a2 = fmaf(w.z, __builtin_amdgcn_rcpf(fmaf(q.z, vv.z, 1.0f)), a2);
      a3 = fmaf(w.w, __builtin_amdgcn_rcpf(fmaf(q.w, vv.w, 1.0f)), a3);
    }
    prt[it & 1][dq][tl] = (a0 + a1) + (a2 + a3);
    __syncthreads();
    if (tid < 64) {
      const float* pp = &prt[it & 1][0][0];
      S[isr1][tc * 64 + tid] =
          (pp[tid] + pp[64 + tid]) + (pp[128 + tid] + pp[192 + tid]);
    }
  }
  __syncthreads();

  // ---- softmax: wave 0 -> r0, wave 1 -> r1 ----
  if (wv < 2) {
    const int row = wv ? r1 : r0;
    const int tb = tl * 4;
    float4 h = *(const float4*)(&S[wv][tb]);
    const int4 mk = *(const int4*)(mask + b * TT + tb);
    float v0 = (tb + 0 >= row && mk.x != 0) ? -2.0f * h.x : -1e30f;
    float v1 = (tb + 1 >= row && mk.y != 0) ? -2.0f * h.y : -1e30f;
    float v2 = (tb + 2 >= row && mk.z != 0) ? -2.0f * h.z : -1e30f;
    float v3 = (tb + 3 >= row && mk.w != 0) ? -2.0f * h.w : -1e30f;
    float mx = fmaxf(fmaxf(v0, v1), fmaxf(v2, v3));
#pragma unroll
    for (int o = 1; o < 64; o <<= 1) mx = fmaxf(mx, __shfl_xor(mx, o));
    float e0 = __expf(v0 - mx), e1 = __expf(v1 - mx),
          e2 = __expf(v2 - mx), e3 = __expf(v3 - mx);
    Pt[tb + 0][wv] = e0; Pt[tb + 1][wv] = e1;
    Pt[tb + 2][wv] = e2; Pt[tb + 3][wv] = e3;
    float sm = (e0 + e1) + (e2 + e3);
#pragma unroll
    for (int o = 1; o < 64; o <<= 1) sm += __shfl_xor(sm, o);
    if (tl == 0) rinvS[wv] = 1.0f / sm;
  }
  __syncthreads();

  // ---- PV: 256 threads x 2 d-cols; loop split at r1 ----
  const int dd = tid * 2;
  const float* mp = mem + ((size_t)b * TT) * DD + dd;
  float ax0 = 0, ay0 = 0, ax1 = 0, ay1 = 0;
#pragma unroll 4
  for (int t = r0; t < r1; ++t) {          // row0 only
    const float p0 = Pt[t][0];
    float2 mv = *(const float2*)(mp + (size_t)t * DD);
    ax0 = fmaf(p0, mv.x, ax0); ay0 = fmaf(p0, mv.y, ay0);
  }
#pragma unroll 4
  for (int t = r1; t < TT; ++t) {          // both rows
    float2 p  = *(const float2*)(&Pt[t][0]);
    float2 mv = *(const float2*)(mp + (size_t)t * DD);
    ax0 = fmaf(p.x, mv.x, ax0); ay0 = fmaf(p.x, mv.y, ay0);
    ax1 = fmaf(p.y, mv.x, ax1); ay1 = fmaf(p.y, mv.y, ay1);
  }
  const float i0 = rinvS[0], i1 = rinvS[1];
  float2 o0 = {ax0 * i0, ay0 * i0};
  float2 o1 = {ax1 * i1, ay1 * i1};
  *(float2*)(out + ((size_t)(b * LL + r0)) * DD + dd) = o0;
  *(float2*)(out + ((size_t)(b * LL + r1)) * DD + dd) = o1;
}

extern "C" void kernel_launch(void* const* d_in, const int* in_sizes, int n_in,
                              void* d_out, int out_size, void* d_ws, size_t ws_size,
                              hipStream_t stream) {
  const float* x   = (const float*)d_in[0];
  const float* mem = (const float*)d_in[1];
  const float* W1  = (const float*)d_in[2];
  const float* b1  = (const float*)d_in[3];
  const float* W2  = (const float*)d_in[4];
  const float* b2  = (const float*)d_in[5];
  const float* wt  = (const float*)d_in[6];
  const int* mask  = (const int*)d_in[8];
  float* outp = (float*)d_out;

  float* E1  = (float*)d_ws;                     // [B*L, D]        2 MB
  float* E2c = E1 + (size_t)BB * LL * DD;        // [D/4][B*T][4]   2 MB (4 MB total)

  proj_gemm<<<dim3((BB * LL + BB * TT) / 32, DD / 64), 256, 0, stream>>>(
      x, mem, W1, b1, W2, b2, E1, E2c);
  fused_attn<<<dim3(LL / 2, BB), 256, 0, stream>>>(E1, E2c, wt, mem, mask, outp);
}